// Round 4
// baseline (129.091 us; speedup 1.0000x reference)
//
#include <hip/hip_runtime.h>
#include <hip/hip_bf16.h>
#include <math.h>

#define BATCH 32
#define IMG 256
#define NCP 9
#define F1P 130              // padded spatial dim of f1 (128 + 2 border)

typedef __attribute__((ext_vector_type(8))) short bf16x8;
typedef __attribute__((ext_vector_type(4))) float f32x4;
typedef __attribute__((ext_vector_type(4))) unsigned int uint4v;

__device__ __constant__ float d_cpx[9] = {-1.f,0.f,1.f,-1.f,0.f,1.f,-1.f,0.f,1.f};
__device__ __constant__ float d_cpy[9] = {-1.f,-1.f,-1.f,0.f,0.f,0.f,1.f,1.f,1.f};

__device__ inline unsigned int pack2bf(float a, float b) {
    __hip_bfloat16 ha = __float2bfloat16(a), hb = __float2bfloat16(b);
    unsigned short ua = *(unsigned short*)&ha, ub = *(unsigned short*)&hb;
    return ((unsigned int)ub << 16) | ua;
}

// ---- conv1 (blocks 0..2047) + prep (blocks 2048..): linv GJ inverse,
//      conv2-weight transpose->bf16, f1 border zeroing ----
__global__ __launch_bounds__(256) void k_conv1p(const float* __restrict__ x,
        const float* __restrict__ w, const float* __restrict__ bias,
        __hip_bfloat16* __restrict__ f1, const float* __restrict__ w2c,
        __hip_bfloat16* __restrict__ wt, float* __restrict__ linv) {
    int blk = blockIdx.x;
    if (blk >= 2048) {
        int pblk = blk - 2048;
        if (pblk == 0) {
            int j = threadIdx.x;
            if (j >= 24) return;
            const float cx[9] = {-1,0,1,-1,0,1,-1,0,1};
            const float cy[9] = {-1,-1,-1,0,0,0,1,1,1};
            float col[12];
            #pragma unroll
            for (int i = 0; i < 12; ++i) {
                float v;
                if (j < 12) {
                    if (i < 9 && j < 9) {
                        float dx = cx[i] - cx[j], dy = cy[i] - cy[j];
                        float r2 = dx * dx + dy * dy;
                        v = (r2 > 0.f) ? r2 * logf(r2) : 0.f;
                    } else if (i < 9) {
                        v = (j == 9) ? 1.f : ((j == 10) ? cx[i] : cy[i]);
                    } else if (j < 9) {
                        v = (i == 9) ? 1.f : ((i == 10) ? cx[j] : cy[j]);
                    } else v = 0.f;
                } else v = (i == j - 12) ? 1.f : 0.f;
                col[i] = v;
            }
            #pragma unroll
            for (int c = 0; c < 12; ++c) {
                float f[12];
                #pragma unroll
                for (int i = 0; i < 12; ++i) f[i] = __shfl(col[i], c);
                int p = c; float best = fabsf(f[c]);
                #pragma unroll
                for (int r = 0; r < 12; ++r) if (r > c) {
                    float a = fabsf(f[r]);
                    bool g = a > best;
                    best = g ? a : best;
                    p = g ? r : p;
                }
                float oldc = col[c], colp = col[c];
                #pragma unroll
                for (int r = 0; r < 12; ++r) colp = (r == p) ? col[r] : colp;
                #pragma unroll
                for (int r = 0; r < 12; ++r) col[r] = (r == p) ? oldc : col[r];
                col[c] = colp;
                float oldfc = f[c], fpv = f[c];
                #pragma unroll
                for (int r = 0; r < 12; ++r) fpv = (r == p) ? f[r] : fpv;
                #pragma unroll
                for (int r = 0; r < 12; ++r) f[r] = (r == p) ? oldfc : f[r];
                f[c] = fpv;
                float inv = 1.0f / f[c];
                col[c] *= inv;
                #pragma unroll
                for (int r = 0; r < 12; ++r) if (r != c) col[r] = fmaf(-f[r], col[c], col[r]);
            }
            if (j >= 12) {
                #pragma unroll
                for (int i = 0; i < 12; ++i) linv[i * 12 + (j - 12)] = col[i];
            }
            return;
        }
        int t = (pblk - 1) * 256 + threadIdx.x;
        if (t < 18432) {
            int pos = t / 2048, rem = t % 2048, oc = rem >> 5, ic = rem & 31;
            wt[t] = __float2bfloat16(w2c[(oc * 32 + ic) * 9 + pos]);
            return;
        }
        int u = t - 18432;
        if (u < 32 * 2064) {
            int b = u / 2064, q = u % 2064;
            int row, px, ch;
            if (q < 520)       { row = 0;   px = q >> 2;         ch = q & 3; }
            else if (q < 1040) { row = 129; px = (q - 520) >> 2; ch = q & 3; }
            else { int z = q - 1040; row = 1 + (z >> 3); int tt = z & 7;
                   px = (tt < 4) ? 0 : 129; ch = tt & 3; }
            uint4v zero = {0, 0, 0, 0};
            size_t eo = ((((size_t)b * F1P + row) * F1P + px) * 32 + ch * 8);
            *(uint4v*)((char*)f1 + eo * 2) = zero;
        }
        return;
    }
    // ---- conv1 (1->32) + maxpool2 + relu -> f1 [b][y+1][x+1][ic] bf16 ----
    int tj = blk & 7, ti = (blk >> 3) & 7, b = blk >> 6;
    __shared__ float tile[34 * 34];
    __shared__ float wl[32 * 9];
    __shared__ float bl[32];
    int tid = threadIdx.x;
    for (int i = tid; i < 32 * 9; i += 256) wl[i] = w[i];
    if (tid < 32) bl[tid] = bias[tid];
    const float* xb = x + (size_t)b * IMG * IMG;
    int oy0 = ti * 32 - 1, ox0 = tj * 32 - 1;
    for (int i = tid; i < 34 * 34; i += 256) {
        int yy = i / 34, xx = i % 34;
        int r = oy0 + yy, c = ox0 + xx;
        float v = 0.f;
        if (r >= 0 && r < IMG && c >= 0 && c < IMG) v = xb[r * IMG + c];
        tile[i] = v;
    }
    __syncthreads();
    int oy = tid >> 4, ox = tid & 15;
    float p[16];
    #pragma unroll
    for (int yy = 0; yy < 4; ++yy)
        #pragma unroll
        for (int xx = 0; xx < 4; ++xx)
            p[yy * 4 + xx] = tile[(2 * oy + yy) * 34 + (2 * ox + xx)];
    int gy = ti * 16 + oy, gx = tj * 16 + ox;
    unsigned int u[16];
    #pragma unroll
    for (int oc2 = 0; oc2 < 16; ++oc2) {
        float vv[2];
        #pragma unroll
        for (int h = 0; h < 2; ++h) {
            int oc = oc2 * 2 + h;
            float ww[9];
            #pragma unroll
            for (int k = 0; k < 9; ++k) ww[k] = wl[oc * 9 + k];
            float m = -INFINITY;
            #pragma unroll
            for (int dy = 0; dy < 2; ++dy)
                #pragma unroll
                for (int dx = 0; dx < 2; ++dx) {
                    float s = 0.f;
                    #pragma unroll
                    for (int ky = 0; ky < 3; ++ky)
                        #pragma unroll
                        for (int kx = 0; kx < 3; ++kx)
                            s = fmaf(p[(dy + ky) * 4 + dx + kx], ww[ky * 3 + kx], s);
                    m = fmaxf(m, s);
                }
            vv[h] = fmaxf(m + bl[oc], 0.f);
        }
        u[oc2] = pack2bf(vv[0], vv[1]);
    }
    size_t eo = (((size_t)b * F1P + (gy + 1)) * F1P + (gx + 1)) * 32;
    uint4v* dst = (uint4v*)((char*)f1 + eo * 2);
    #pragma unroll
    for (int q = 0; q < 4; ++q) {
        uint4v vq = { u[q*4+0], u[q*4+1], u[q*4+2], u[q*4+3] };
        dst[q] = vq;
    }
}

// -------- conv2: direct-load MFMA implicit GEMM, all 64 oc per block --------
// block = (b, region); region = 32x32 conv px = one 16x16 avgpool block.
__global__ __launch_bounds__(256, 2) void k_conv2m(const __hip_bfloat16* __restrict__ f1,
        const __hip_bfloat16* __restrict__ wt, const float* __restrict__ bias,
        float* __restrict__ feat) {
    __shared__ float red[4][64];
    int tid = threadIdx.x;
    int w = tid >> 6, l = tid & 63;
    int lr = l & 15, lg = l >> 4;
    int blk = blockIdx.x;
    int region = blk & 15;
    int b = blk >> 4;
    int ry = region >> 2, rx = region & 3;
    const __hip_bfloat16* f1b = f1 + (size_t)b * F1P * F1P * 32;

    // weight fragments: lane holds oc = n*16 + lr, ic = lg*8..lg*8+7
    bf16x8 Bf[4][9];
    #pragma unroll
    for (int n = 0; n < 4; ++n)
        #pragma unroll
        for (int p = 0; p < 9; ++p)
            Bf[n][p] = *(const bf16x8*)(wt + ((size_t)(p * 64 + n * 16 + lr) * 32 + lg * 8));
    float biasv[4];
    #pragma unroll
    for (int n = 0; n < 4; ++n) biasv[n] = bias[n * 16 + lr];

    float fsum[4] = {0.f, 0.f, 0.f, 0.f};

    #pragma unroll 1
    for (int b4 = 0; b4 < 4; ++b4) {
        int pr = b4 * 4 + w;                   // pooled row 0..15 in region
        int row0 = ry * 32 + 2 * pr;           // padded f1 row base
        #pragma unroll
        for (int xt = 0; xt < 2; ++xt) {
            int x0 = rx * 32 + xt * 16 + lr;   // padded x
            bf16x8 Af[4][3];
            #pragma unroll
            for (int rr = 0; rr < 4; ++rr)
                #pragma unroll
                for (int dx = 0; dx < 3; ++dx)
                    Af[rr][dx] = *(const bf16x8*)(f1b + ((size_t)(row0 + rr) * F1P + x0 + dx) * 32 + lg * 8);
            #pragma unroll
            for (int n = 0; n < 4; ++n) {
                f32x4 a0 = {0.f, 0.f, 0.f, 0.f}, a1 = {0.f, 0.f, 0.f, 0.f};
                #pragma unroll
                for (int dy = 0; dy < 3; ++dy)
                    #pragma unroll
                    for (int dx = 0; dx < 3; ++dx) {
                        a0 = __builtin_amdgcn_mfma_f32_16x16x32_bf16(Af[dy][dx],     Bf[n][dy * 3 + dx], a0, 0, 0, 0);
                        a1 = __builtin_amdgcn_mfma_f32_16x16x32_bf16(Af[dy + 1][dx], Bf[n][dy * 3 + dx], a1, 0, 0, 0);
                    }
                float p0 = fmaxf(fmaxf(a0[0], a0[1]), fmaxf(a1[0], a1[1]));
                float p1 = fmaxf(fmaxf(a0[2], a0[3]), fmaxf(a1[2], a1[3]));
                fsum[n] += fmaxf(p0 + biasv[n], 0.f) + fmaxf(p1 + biasv[n], 0.f);
            }
        }
    }

    #pragma unroll
    for (int n = 0; n < 4; ++n) {
        fsum[n] += __shfl_xor(fsum[n], 16);
        fsum[n] += __shfl_xor(fsum[n], 32);
    }
    if (l < 16) {
        #pragma unroll
        for (int n = 0; n < 4; ++n) red[w][n * 16 + l] = fsum[n];
    }
    __syncthreads();
    if (tid < 64) {
        float s = red[0][tid] + red[1][tid] + red[2][tid] + red[3][tid];
        feat[(size_t)b * 1024 + tid * 16 + region] = s * (1.0f / 256.0f);
    }
}

// ---- fc1 (1024->256) + relu + fc2 (256->18) + Y + Wfull = Linv @ Y ----
// one block per batch, 1024 threads (16 waves), h kept in LDS.
__global__ __launch_bounds__(1024) void k_fchead(const float* __restrict__ feat,
        const float* __restrict__ w1, const float* __restrict__ b1,
        const float* __restrict__ w2, const float* __restrict__ b2,
        const float* __restrict__ linv, float* __restrict__ wfull) {
    int b = blockIdx.x;
    int t = threadIdx.x;
    int w = t >> 6, l = t & 63;
    __shared__ float sfeat[1024];
    __shared__ float hl[256];
    __shared__ float L[144];
    __shared__ float Y[24];
    sfeat[t] = feat[(size_t)b * 1024 + t];
    if (t < 144) L[t] = linv[t];
    __syncthreads();
    #pragma unroll 1
    for (int jj = 0; jj < 16; ++jj) {
        int j = w * 16 + jj;
        const float* wr = w1 + (size_t)j * 1024;
        float s = 0.f;
        #pragma unroll
        for (int k = l; k < 1024; k += 64) s = fmaf(wr[k], sfeat[k], s);
        #pragma unroll
        for (int off = 32; off; off >>= 1) s += __shfl_xor(s, off);
        if (l == 0) hl[j] = fmaxf(s + b1[j], 0.f);
    }
    __syncthreads();
    if (t < 18) {
        const float* wr = w2 + (size_t)t * 256;
        float s = 0.f;
        for (int k = 0; k < 256; ++k) s = fmaf(wr[k], hl[k], s);
        s += b2[t];
        int kk = t >> 1, d = t & 1;
        float cp = (d == 0) ? d_cpx[kk] : d_cpy[kk];
        Y[t] = cp + s;
    }
    if (t >= 18 && t < 24) Y[t] = 0.f;
    __syncthreads();
    if (t < 24) {
        int i = t >> 1, d = t & 1;
        float s = 0.f;
        #pragma unroll
        for (int k = 0; k < 12; ++k) s = fmaf(L[i * 12 + k], Y[k * 2 + d], s);
        wfull[b * 24 + t] = s;
    }
}

// -------- fused TPS-grid eval + bilinear grid_sample, 8 batches per block --------
// grid: (py, bgroup); U (9 logf) computed once per pixel, reused across 8 batches.
__global__ __launch_bounds__(256) void k_sample(const float* __restrict__ x,
        const float* __restrict__ wfull, float* __restrict__ out) {
    int py = blockIdx.x & 255;
    int bg = blockIdx.x >> 8;          // 0..3
    int px = threadIdx.x;
    __shared__ float Wf[8][24];
    if (threadIdx.x < 192) {
        int bi = threadIdx.x / 24, q = threadIdx.x % 24;
        Wf[bi][q] = wfull[(bg * 8 + bi) * 24 + q];
    }
    __syncthreads();
    float gx = px * (2.0f / 255.0f) - 1.0f;
    float gy = py * (2.0f / 255.0f) - 1.0f;
    float U[9];
    #pragma unroll
    for (int k = 0; k < 9; ++k) {
        float dx = gx - d_cpx[k], dy = gy - d_cpy[k];
        float r2 = dx * dx + dy * dy;
        U[k] = (r2 > 0.f) ? r2 * logf(r2) : 0.f;
    }
    #pragma unroll
    for (int bi = 0; bi < 8; ++bi) {
        int b = bg * 8 + bi;
        float sx = Wf[bi][18] + Wf[bi][20] * gx + Wf[bi][22] * gy;
        float sy = Wf[bi][19] + Wf[bi][21] * gx + Wf[bi][23] * gy;
        #pragma unroll
        for (int k = 0; k < 9; ++k) {
            sx = fmaf(U[k], Wf[bi][k * 2 + 0], sx);
            sy = fmaf(U[k], Wf[bi][k * 2 + 1], sy);
        }
        float xp = (sx + 1.0f) * 0.5f * 255.0f;
        float yp = (sy + 1.0f) * 0.5f * 255.0f;
        float x0f = floorf(xp), y0f = floorf(yp);
        float wx = xp - x0f, wy = yp - y0f;
        int x0 = (int)x0f, y0 = (int)y0f;
        const float* xb = x + (size_t)b * IMG * IMG;
        float v00, v10, v01, v11;
        {
            int ix, iy; bool valid; int ixc, iyc;
            ix = x0;     iy = y0;
            valid = (ix >= 0) && (ix < IMG) && (iy >= 0) && (iy < IMG);
            ixc = min(max(ix, 0), IMG - 1); iyc = min(max(iy, 0), IMG - 1);
            v00 = valid ? xb[iyc * IMG + ixc] : 0.f;
            ix = x0 + 1; iy = y0;
            valid = (ix >= 0) && (ix < IMG) && (iy >= 0) && (iy < IMG);
            ixc = min(max(ix, 0), IMG - 1); iyc = min(max(iy, 0), IMG - 1);
            v10 = valid ? xb[iyc * IMG + ixc] : 0.f;
            ix = x0;     iy = y0 + 1;
            valid = (ix >= 0) && (ix < IMG) && (iy >= 0) && (iy < IMG);
            ixc = min(max(ix, 0), IMG - 1); iyc = min(max(iy, 0), IMG - 1);
            v01 = valid ? xb[iyc * IMG + ixc] : 0.f;
            ix = x0 + 1; iy = y0 + 1;
            valid = (ix >= 0) && (ix < IMG) && (iy >= 0) && (iy < IMG);
            ixc = min(max(ix, 0), IMG - 1); iyc = min(max(iy, 0), IMG - 1);
            v11 = valid ? xb[iyc * IMG + ixc] : 0.f;
        }
        float r = v00 * (1.f - wx) * (1.f - wy) + v10 * wx * (1.f - wy)
                + v01 * (1.f - wx) * wy        + v11 * wx * wy;
        out[(size_t)b * IMG * IMG + py * IMG + px] = r;
    }
}

extern "C" void kernel_launch(void* const* d_in, const int* in_sizes, int n_in,
                              void* d_out, int out_size, void* d_ws, size_t ws_size,
                              hipStream_t stream) {
    const float* x   = (const float*)d_in[0];
    const float* c1w = (const float*)d_in[1];
    const float* c1b = (const float*)d_in[2];
    const float* c2w = (const float*)d_in[3];
    const float* c2b = (const float*)d_in[4];
    const float* w1  = (const float*)d_in[5];
    const float* b1  = (const float*)d_in[6];
    const float* w2  = (const float*)d_in[7];
    const float* b2  = (const float*)d_in[8];
    float* out = (float*)d_out;

    __hip_bfloat16* f1 = (__hip_bfloat16*)d_ws;              // 32*130*130*32 bf16
    __hip_bfloat16* wt = f1 + (size_t)32 * F1P * F1P * 32;   // 18432 bf16
    float* fbase = (float*)(wt + 18432);
    float* feat  = fbase;            // 32*1024
    float* wfull = feat + 32768;     // 32*24
    float* linv  = wfull + 768;      // 144

    k_conv1p<<<2048 + 331, 256, 0, stream>>>(x, c1w, c1b, f1, c2w, wt, linv);
    k_conv2m<<<BATCH * 16, 256, 0, stream>>>(f1, wt, c2b, feat);
    k_fchead<<<BATCH, 1024, 0, stream>>>(feat, w1, b1, w2, b2, linv, wfull);
    k_sample<<<1024, 256, 0, stream>>>(x, wfull, out);
}

// Round 5
// 67.485 us; speedup vs baseline: 1.9129x; 1.9129x over previous
//
#include <hip/hip_runtime.h>
#include <hip/hip_bf16.h>
#include <math.h>

#define BATCH 32
#define IMG 256
#define NCP 9
#define F1P 130              // padded spatial dim of f1 (128 + 2 border)

typedef __attribute__((ext_vector_type(8))) short bf16x8;
typedef __attribute__((ext_vector_type(4))) float f32x4;
typedef __attribute__((ext_vector_type(4))) unsigned int uint4v;

__device__ __constant__ float d_cpx[9] = {-1.f,0.f,1.f,-1.f,0.f,1.f,-1.f,0.f,1.f};
__device__ __constant__ float d_cpy[9] = {-1.f,-1.f,-1.f,0.f,0.f,0.f,1.f,1.f,1.f};

__device__ inline unsigned int pack2bf(float a, float b) {
    __hip_bfloat16 ha = __float2bfloat16(a), hb = __float2bfloat16(b);
    unsigned short ua = *(unsigned short*)&ha, ub = *(unsigned short*)&hb;
    return ((unsigned int)ub << 16) | ua;
}

// ---- conv1 (blocks 0..2047) + prep (blocks 2048..): linv GJ inverse,
//      conv2-weight transpose->bf16, f1 border zeroing ----
__global__ __launch_bounds__(256) void k_conv1p(const float* __restrict__ x,
        const float* __restrict__ w, const float* __restrict__ bias,
        __hip_bfloat16* __restrict__ f1, const float* __restrict__ w2c,
        __hip_bfloat16* __restrict__ wt, float* __restrict__ linv) {
    int blk = blockIdx.x;
    if (blk >= 2048) {
        int pblk = blk - 2048;
        if (pblk == 0) {
            int j = threadIdx.x;
            if (j >= 24) return;
            const float cx[9] = {-1,0,1,-1,0,1,-1,0,1};
            const float cy[9] = {-1,-1,-1,0,0,0,1,1,1};
            float col[12];
            #pragma unroll
            for (int i = 0; i < 12; ++i) {
                float v;
                if (j < 12) {
                    if (i < 9 && j < 9) {
                        float dx = cx[i] - cx[j], dy = cy[i] - cy[j];
                        float r2 = dx * dx + dy * dy;
                        v = (r2 > 0.f) ? r2 * logf(r2) : 0.f;
                    } else if (i < 9) {
                        v = (j == 9) ? 1.f : ((j == 10) ? cx[i] : cy[i]);
                    } else if (j < 9) {
                        v = (i == 9) ? 1.f : ((i == 10) ? cx[j] : cy[j]);
                    } else v = 0.f;
                } else v = (i == j - 12) ? 1.f : 0.f;
                col[i] = v;
            }
            #pragma unroll
            for (int c = 0; c < 12; ++c) {
                float f[12];
                #pragma unroll
                for (int i = 0; i < 12; ++i) f[i] = __shfl(col[i], c);
                int p = c; float best = fabsf(f[c]);
                #pragma unroll
                for (int r = 0; r < 12; ++r) if (r > c) {
                    float a = fabsf(f[r]);
                    bool g = a > best;
                    best = g ? a : best;
                    p = g ? r : p;
                }
                float oldc = col[c], colp = col[c];
                #pragma unroll
                for (int r = 0; r < 12; ++r) colp = (r == p) ? col[r] : colp;
                #pragma unroll
                for (int r = 0; r < 12; ++r) col[r] = (r == p) ? oldc : col[r];
                col[c] = colp;
                float oldfc = f[c], fpv = f[c];
                #pragma unroll
                for (int r = 0; r < 12; ++r) fpv = (r == p) ? f[r] : fpv;
                #pragma unroll
                for (int r = 0; r < 12; ++r) f[r] = (r == p) ? oldfc : f[r];
                f[c] = fpv;
                float inv = 1.0f / f[c];
                col[c] *= inv;
                #pragma unroll
                for (int r = 0; r < 12; ++r) if (r != c) col[r] = fmaf(-f[r], col[c], col[r]);
            }
            if (j >= 12) {
                #pragma unroll
                for (int i = 0; i < 12; ++i) linv[i * 12 + (j - 12)] = col[i];
            }
            return;
        }
        int t = (pblk - 1) * 256 + threadIdx.x;
        if (t < 18432) {
            int pos = t / 2048, rem = t % 2048, oc = rem >> 5, ic = rem & 31;
            wt[t] = __float2bfloat16(w2c[(oc * 32 + ic) * 9 + pos]);
            return;
        }
        int u = t - 18432;
        if (u < 32 * 2064) {
            int b = u / 2064, q = u % 2064;
            int row, px, ch;
            if (q < 520)       { row = 0;   px = q >> 2;         ch = q & 3; }
            else if (q < 1040) { row = 129; px = (q - 520) >> 2; ch = q & 3; }
            else { int z = q - 1040; row = 1 + (z >> 3); int tt = z & 7;
                   px = (tt < 4) ? 0 : 129; ch = tt & 3; }
            uint4v zero = {0, 0, 0, 0};
            size_t eo = ((((size_t)b * F1P + row) * F1P + px) * 32 + ch * 8);
            *(uint4v*)((char*)f1 + eo * 2) = zero;
        }
        return;
    }
    // ---- conv1 (1->32) + maxpool2 + relu -> f1 [b][y+1][x+1][ic] bf16 ----
    int tj = blk & 7, ti = (blk >> 3) & 7, b = blk >> 6;
    __shared__ float tile[34 * 34];
    __shared__ float wl[32 * 9];
    __shared__ float bl[32];
    int tid = threadIdx.x;
    for (int i = tid; i < 32 * 9; i += 256) wl[i] = w[i];
    if (tid < 32) bl[tid] = bias[tid];
    const float* xb = x + (size_t)b * IMG * IMG;
    int oy0 = ti * 32 - 1, ox0 = tj * 32 - 1;
    for (int i = tid; i < 34 * 34; i += 256) {
        int yy = i / 34, xx = i % 34;
        int r = oy0 + yy, c = ox0 + xx;
        float v = 0.f;
        if (r >= 0 && r < IMG && c >= 0 && c < IMG) v = xb[r * IMG + c];
        tile[i] = v;
    }
    __syncthreads();
    int oy = tid >> 4, ox = tid & 15;
    float p[16];
    #pragma unroll
    for (int yy = 0; yy < 4; ++yy)
        #pragma unroll
        for (int xx = 0; xx < 4; ++xx)
            p[yy * 4 + xx] = tile[(2 * oy + yy) * 34 + (2 * ox + xx)];
    int gy = ti * 16 + oy, gx = tj * 16 + ox;
    unsigned int u[16];
    #pragma unroll
    for (int oc2 = 0; oc2 < 16; ++oc2) {
        float vv[2];
        #pragma unroll
        for (int h = 0; h < 2; ++h) {
            int oc = oc2 * 2 + h;
            float ww[9];
            #pragma unroll
            for (int k = 0; k < 9; ++k) ww[k] = wl[oc * 9 + k];
            float m = -INFINITY;
            #pragma unroll
            for (int dy = 0; dy < 2; ++dy)
                #pragma unroll
                for (int dx = 0; dx < 2; ++dx) {
                    float s = 0.f;
                    #pragma unroll
                    for (int ky = 0; ky < 3; ++ky)
                        #pragma unroll
                        for (int kx = 0; kx < 3; ++kx)
                            s = fmaf(p[(dy + ky) * 4 + dx + kx], ww[ky * 3 + kx], s);
                    m = fmaxf(m, s);
                }
            vv[h] = fmaxf(m + bl[oc], 0.f);
        }
        u[oc2] = pack2bf(vv[0], vv[1]);
    }
    size_t eo = (((size_t)b * F1P + (gy + 1)) * F1P + (gx + 1)) * 32;
    uint4v* dst = (uint4v*)((char*)f1 + eo * 2);
    #pragma unroll
    for (int q = 0; q < 4; ++q) {
        uint4v vq = { u[q*4+0], u[q*4+1], u[q*4+2], u[q*4+3] };
        dst[q] = vq;
    }
}

// -------- conv2: direct-load MFMA implicit GEMM, all 64 oc per block --------
// block = (b, region); region = 32x32 conv px = one 16x16 avgpool block.
__global__ __launch_bounds__(256, 2) void k_conv2m(const __hip_bfloat16* __restrict__ f1,
        const __hip_bfloat16* __restrict__ wt, const float* __restrict__ bias,
        float* __restrict__ feat) {
    __shared__ float red[4][64];
    int tid = threadIdx.x;
    int w = tid >> 6, l = tid & 63;
    int lr = l & 15, lg = l >> 4;
    int blk = blockIdx.x;
    int region = blk & 15;
    int b = blk >> 4;
    int ry = region >> 2, rx = region & 3;
    const __hip_bfloat16* f1b = f1 + (size_t)b * F1P * F1P * 32;

    // weight fragments: lane holds oc = n*16 + lr, ic = lg*8..lg*8+7
    bf16x8 Bf[4][9];
    #pragma unroll
    for (int n = 0; n < 4; ++n)
        #pragma unroll
        for (int p = 0; p < 9; ++p)
            Bf[n][p] = *(const bf16x8*)(wt + ((size_t)(p * 64 + n * 16 + lr) * 32 + lg * 8));
    float biasv[4];
    #pragma unroll
    for (int n = 0; n < 4; ++n) biasv[n] = bias[n * 16 + lr];

    float fsum[4] = {0.f, 0.f, 0.f, 0.f};

    #pragma unroll 1
    for (int b4 = 0; b4 < 4; ++b4) {
        int pr = b4 * 4 + w;                   // pooled row 0..15 in region
        int row0 = ry * 32 + 2 * pr;           // padded f1 row base
        #pragma unroll
        for (int xt = 0; xt < 2; ++xt) {
            int x0 = rx * 32 + xt * 16 + lr;   // padded x
            bf16x8 Af[4][3];
            #pragma unroll
            for (int rr = 0; rr < 4; ++rr)
                #pragma unroll
                for (int dx = 0; dx < 3; ++dx)
                    Af[rr][dx] = *(const bf16x8*)(f1b + ((size_t)(row0 + rr) * F1P + x0 + dx) * 32 + lg * 8);
            #pragma unroll
            for (int n = 0; n < 4; ++n) {
                f32x4 a0 = {0.f, 0.f, 0.f, 0.f}, a1 = {0.f, 0.f, 0.f, 0.f};
                #pragma unroll
                for (int dy = 0; dy < 3; ++dy)
                    #pragma unroll
                    for (int dx = 0; dx < 3; ++dx) {
                        a0 = __builtin_amdgcn_mfma_f32_16x16x32_bf16(Af[dy][dx],     Bf[n][dy * 3 + dx], a0, 0, 0, 0);
                        a1 = __builtin_amdgcn_mfma_f32_16x16x32_bf16(Af[dy + 1][dx], Bf[n][dy * 3 + dx], a1, 0, 0, 0);
                    }
                float p0 = fmaxf(fmaxf(a0[0], a0[1]), fmaxf(a1[0], a1[1]));
                float p1 = fmaxf(fmaxf(a0[2], a0[3]), fmaxf(a1[2], a1[3]));
                fsum[n] += fmaxf(p0 + biasv[n], 0.f) + fmaxf(p1 + biasv[n], 0.f);
            }
        }
    }

    #pragma unroll
    for (int n = 0; n < 4; ++n) {
        fsum[n] += __shfl_xor(fsum[n], 16);
        fsum[n] += __shfl_xor(fsum[n], 32);
    }
    if (l < 16) {
        #pragma unroll
        for (int n = 0; n < 4; ++n) red[w][n * 16 + l] = fsum[n];
    }
    __syncthreads();
    if (tid < 64) {
        float s = red[0][tid] + red[1][tid] + red[2][tid] + red[3][tid];
        feat[(size_t)b * 1024 + tid * 16 + region] = s * (1.0f / 256.0f);
    }
}

// ---------------- fc1 (1024->256) + relu: one wave per output ----------------
__global__ __launch_bounds__(256) void k_fc1(const float* __restrict__ feat,
        const float* __restrict__ w, const float* __restrict__ bias,
        float* __restrict__ h) {
    int wave = threadIdx.x >> 6, lane = threadIdx.x & 63;
    int o = blockIdx.x * 4 + wave;           // o in [0, 8192)
    int b = o >> 8, j = o & 255;
    const float4* wr = (const float4*)(w + (size_t)j * 1024);
    const float4* fb = (const float4*)(feat + (size_t)b * 1024);
    float s = 0.f;
    #pragma unroll
    for (int i = 0; i < 4; ++i) {
        float4 a = wr[lane + i * 64];
        float4 c = fb[lane + i * 64];
        s = fmaf(a.x, c.x, s); s = fmaf(a.y, c.y, s);
        s = fmaf(a.z, c.z, s); s = fmaf(a.w, c.w, s);
    }
    #pragma unroll
    for (int off = 32; off; off >>= 1) s += __shfl_xor(s, off);
    if (lane == 0) h[o] = fmaxf(s + bias[j], 0.f);
}

// -------- fc2 (256->18) + Y build + Wfull = Linv @ Y ----------
__global__ __launch_bounds__(64) void k_head(const float* __restrict__ h,
        const float* __restrict__ w2, const float* __restrict__ b2,
        const float* __restrict__ linv, float* __restrict__ wfull) {
    int b = blockIdx.x;
    int t = threadIdx.x;
    __shared__ float Y[12][2];
    __shared__ float L[144];
    const float* hb = h + (size_t)b * 256;
    for (int i = t; i < 144; i += 64) L[i] = linv[i];
    if (t < 18) {
        const float* wr = w2 + (size_t)t * 256;
        float s = 0.f;
        for (int k = 0; k < 256; ++k) s = fmaf(wr[k], hb[k], s);
        s += b2[t];
        int kk = t >> 1, d = t & 1;
        float cp = (d == 0) ? d_cpx[kk] : d_cpy[kk];
        Y[kk][d] = cp + s;
    }
    if (t >= 18 && t < 24) Y[9 + ((t - 18) >> 1)][(t - 18) & 1] = 0.f;
    __syncthreads();
    if (t < 24) {
        int i = t >> 1, d = t & 1;
        float s = 0.f;
        #pragma unroll
        for (int k = 0; k < 12; ++k) s = fmaf(L[i * 12 + k], Y[k][d], s);
        wfull[b * 24 + i * 2 + d] = s;
    }
}

// -------- fused TPS-grid eval + bilinear grid_sample, 8 batches per block --------
// grid: (py, bgroup); U (9 logf) computed once per pixel, reused across 8 batches.
__global__ __launch_bounds__(256) void k_sample(const float* __restrict__ x,
        const float* __restrict__ wfull, float* __restrict__ out) {
    int py = blockIdx.x & 255;
    int bg = blockIdx.x >> 8;          // 0..3
    int px = threadIdx.x;
    __shared__ float Wf[8][24];
    if (threadIdx.x < 192) {
        int bi = threadIdx.x / 24, q = threadIdx.x % 24;
        Wf[bi][q] = wfull[(bg * 8 + bi) * 24 + q];
    }
    __syncthreads();
    float gx = px * (2.0f / 255.0f) - 1.0f;
    float gy = py * (2.0f / 255.0f) - 1.0f;
    float U[9];
    #pragma unroll
    for (int k = 0; k < 9; ++k) {
        float dx = gx - d_cpx[k], dy = gy - d_cpy[k];
        float r2 = dx * dx + dy * dy;
        U[k] = (r2 > 0.f) ? r2 * logf(r2) : 0.f;
    }
    #pragma unroll
    for (int bi = 0; bi < 8; ++bi) {
        int b = bg * 8 + bi;
        float sx = Wf[bi][18] + Wf[bi][20] * gx + Wf[bi][22] * gy;
        float sy = Wf[bi][19] + Wf[bi][21] * gx + Wf[bi][23] * gy;
        #pragma unroll
        for (int k = 0; k < 9; ++k) {
            sx = fmaf(U[k], Wf[bi][k * 2 + 0], sx);
            sy = fmaf(U[k], Wf[bi][k * 2 + 1], sy);
        }
        float xp = (sx + 1.0f) * 0.5f * 255.0f;
        float yp = (sy + 1.0f) * 0.5f * 255.0f;
        float x0f = floorf(xp), y0f = floorf(yp);
        float wx = xp - x0f, wy = yp - y0f;
        int x0 = (int)x0f, y0 = (int)y0f;
        const float* xb = x + (size_t)b * IMG * IMG;
        float v00, v10, v01, v11;
        {
            int ix, iy; bool valid; int ixc, iyc;
            ix = x0;     iy = y0;
            valid = (ix >= 0) && (ix < IMG) && (iy >= 0) && (iy < IMG);
            ixc = min(max(ix, 0), IMG - 1); iyc = min(max(iy, 0), IMG - 1);
            v00 = valid ? xb[iyc * IMG + ixc] : 0.f;
            ix = x0 + 1; iy = y0;
            valid = (ix >= 0) && (ix < IMG) && (iy >= 0) && (iy < IMG);
            ixc = min(max(ix, 0), IMG - 1); iyc = min(max(iy, 0), IMG - 1);
            v10 = valid ? xb[iyc * IMG + ixc] : 0.f;
            ix = x0;     iy = y0 + 1;
            valid = (ix >= 0) && (ix < IMG) && (iy >= 0) && (iy < IMG);
            ixc = min(max(ix, 0), IMG - 1); iyc = min(max(iy, 0), IMG - 1);
            v01 = valid ? xb[iyc * IMG + ixc] : 0.f;
            ix = x0 + 1; iy = y0 + 1;
            valid = (ix >= 0) && (ix < IMG) && (iy >= 0) && (iy < IMG);
            ixc = min(max(ix, 0), IMG - 1); iyc = min(max(iy, 0), IMG - 1);
            v11 = valid ? xb[iyc * IMG + ixc] : 0.f;
        }
        float r = v00 * (1.f - wx) * (1.f - wy) + v10 * wx * (1.f - wy)
                + v01 * (1.f - wx) * wy        + v11 * wx * wy;
        out[(size_t)b * IMG * IMG + py * IMG + px] = r;
    }
}

extern "C" void kernel_launch(void* const* d_in, const int* in_sizes, int n_in,
                              void* d_out, int out_size, void* d_ws, size_t ws_size,
                              hipStream_t stream) {
    const float* x   = (const float*)d_in[0];
    const float* c1w = (const float*)d_in[1];
    const float* c1b = (const float*)d_in[2];
    const float* c2w = (const float*)d_in[3];
    const float* c2b = (const float*)d_in[4];
    const float* w1  = (const float*)d_in[5];
    const float* b1  = (const float*)d_in[6];
    const float* w2  = (const float*)d_in[7];
    const float* b2  = (const float*)d_in[8];
    float* out = (float*)d_out;

    __hip_bfloat16* f1 = (__hip_bfloat16*)d_ws;              // 32*130*130*32 bf16
    __hip_bfloat16* wt = f1 + (size_t)32 * F1P * F1P * 32;   // 18432 bf16
    float* fbase = (float*)(wt + 18432);
    float* feat  = fbase;            // 32*1024
    float* hbuf  = feat + 32768;     // 32*256
    float* wfull = hbuf + 8192;      // 32*24
    float* linv  = wfull + 768;      // 144

    k_conv1p<<<2048 + 331, 256, 0, stream>>>(x, c1w, c1b, f1, c2w, wt, linv);
    k_conv2m<<<BATCH * 16, 256, 0, stream>>>(f1, wt, c2b, feat);
    k_fc1   <<<2048, 256, 0, stream>>>(feat, w1, b1, hbuf);
    k_head  <<<BATCH, 64, 0, stream>>>(hbuf, w2, b2, linv, wfull);
    k_sample<<<1024, 256, 0, stream>>>(x, wfull, out);
}